// Round 4
// baseline (99.728 us; speedup 1.0000x reference)
//
#include <hip/hip_runtime.h>
#include <math.h>

#define CLIPV 0.03f

struct W9 { float g[9]; };

__device__ __forceinline__ int reflect_idx(int i, int n) {
    if (i < 0) i = -i;
    if (i >= n) i = 2 * n - 2 - i;
    return i;
}

// ---------------------------------------------------------------------------
// Zero-barrier fused separable 3-D Gaussian (K=9) + clip.
// One wave (64 threads) per block; tile = 8 rows x 32 cols, z-chunk 32 planes.
// Per z-step (all wave-private, program-order DS => no __syncthreads):
//   - issue 6 float4 global loads of NEXT plane's raw rows (regs)
//   - ds_read 12 floats (3x b128) of W-conv column written LAST iter
//   - H-conv (vertical 4-stack) -> 9-deep float4 register ring -> D-conv
//     + clip (scalar x loads, L2-hot) + store
//   - W-conv for next plane in registers -> 8x ds_write_b32 transposed
// LDS: sTt[32 cols][16 rows + 4 pad] = 2.5 KB, single buffer.
// Grid: 8 z-chunks (bid&7 == XCD) x 256 tiles = 2048 single-wave blocks.
// ---------------------------------------------------------------------------
__global__ __launch_bounds__(64) void smooth3d_wave(const float* __restrict__ x,
                                                    float* __restrict__ out, W9 wt) {
    __shared__ float sTt[32][20];   // [col][w-conv row 0..15], stride 20 (bank spread)

    const int bid   = blockIdx.x;
    const int chunk = bid & 7;          // z-chunk; == XCD under %8 round-robin
    const int tile  = bid >> 3;         // 0..255
    const int wb = (tile & 7) * 32;
    const int hb = (tile >> 3) * 8;
    const int z0 = chunk * 32;

    const int L  = threadIdx.x;         // lane
    const int r  = L >> 2;              // stage1 row 0..15 (raw row hb-4+r)
    const int q  = L & 3;               // stage1 col group
    const int hq = L >> 5;              // stage2 row-quad 0..1
    const int c  = L & 31;              // stage2 col

    // ---- z-invariant per-lane geometry ----
    const int gr  = reflect_idx(hb - 4 + r, 256);
    const int wb4 = wb >> 2;

    int goff[6];       // float offsets (within a plane) of the 6 raw float4 loads
    int oslot = -1;    // at most ONE load slot per lane needs scalar reflect
    int soff[4] = {0, 0, 0, 0};
    #pragma unroll
    for (int s = 0; s < 6; ++s) {
        int rel = q + (s < 3 ? s : s + 1);      // q,q+1,q+2, q+4,q+5,q+6
        int gc4 = wb4 - 1 + rel;
        if (gc4 < 0 || gc4 > 63) {
            oslot = s;
            #pragma unroll
            for (int k = 0; k < 4; ++k)
                soff[k] = gr * 256 + reflect_idx(wb - 4 + rel * 4 + k, 256);
            goff[s] = gr * 256;                 // unused
        } else {
            goff[s] = gr * 256 + gc4 * 4;
        }
    }

    int ooff[4];       // output/clip offsets (within a plane), vertical 4-stack
    #pragma unroll
    for (int e = 0; e < 4; ++e)
        ooff[e] = (hb + 4 * hq + e) * 256 + wb + c;

    float4 ld[6];
    auto load_raw = [&](const float* plane) {
        #pragma unroll
        for (int s = 0; s < 6; ++s) {
            if (s == oslot) {
                float4 v;
                v.x = plane[soff[0]]; v.y = plane[soff[1]];
                v.z = plane[soff[2]]; v.w = plane[soff[3]];
                ld[s] = v;
            } else {
                ld[s] = *(const float4*)(plane + goff[s]);
            }
        }
    };

    auto wconv_write = [&]() {
        // output f4 #0 at cols 4q..4q+3 from ld[0..2]
        {
            float sv[12] = {ld[0].x, ld[0].y, ld[0].z, ld[0].w,
                            ld[1].x, ld[1].y, ld[1].z, ld[1].w,
                            ld[2].x, ld[2].y, ld[2].z, ld[2].w};
            #pragma unroll
            for (int e = 0; e < 4; ++e) {
                float a = 0.f;
                #pragma unroll
                for (int j = 0; j < 9; ++j) a = fmaf(wt.g[j], sv[e + j], a);
                sTt[4 * q + e][r] = a;
            }
        }
        // output f4 #1 at cols 4q+16..4q+19 from ld[3..5]
        {
            float sv[12] = {ld[3].x, ld[3].y, ld[3].z, ld[3].w,
                            ld[4].x, ld[4].y, ld[4].z, ld[4].w,
                            ld[5].x, ld[5].y, ld[5].z, ld[5].w};
            #pragma unroll
            for (int e = 0; e < 4; ++e) {
                float a = 0.f;
                #pragma unroll
                for (int j = 0; j < 9; ++j) a = fmaf(wt.g[j], sv[e + j], a);
                sTt[4 * q + 16 + e][r] = a;
            }
        }
    };

    // ---- prologue: plane z0-4 through W-conv into sTt ----
    load_raw(x + (size_t)reflect_idx(z0 - 4, 256) * 65536);
    wconv_write();

    float4 ring[9];
    #pragma unroll
    for (int k = 0; k < 9; ++k) { ring[k].x = 0.f; ring[k].y = 0.f; ring[k].z = 0.f; ring[k].w = 0.f; }

    for (int i = 0; i < 40; ++i) {
        // issue next plane's raw loads (consumed at bottom of this iteration)
        if (i < 39)
            load_raw(x + (size_t)reflect_idx(z0 - 3 + i, 256) * 65536);

        // clip-source loads for this step's output plane (L2-hot, issued early)
        const int zo = z0 + i - 8;
        float cx[4];
        if (i >= 8) {
            const float* pz = x + (size_t)zo * 65536;
            #pragma unroll
            for (int e = 0; e < 4; ++e) cx[e] = pz[ooff[e]];
        }

        // read W-conv column (written previous iteration; latency long gone)
        float4 v0 = *(const float4*)&sTt[c][4 * hq];
        float4 v1 = *(const float4*)&sTt[c][4 * hq + 4];
        float4 v2 = *(const float4*)&sTt[c][4 * hq + 8];
        float vv[12] = {v0.x, v0.y, v0.z, v0.w, v1.x, v1.y, v1.z, v1.w,
                        v2.x, v2.y, v2.z, v2.w};

        // H-conv -> vertical float4 (rows 4hq..4hq+3 at col c)
        float4 wv;
        {
            float a0 = 0.f, a1 = 0.f, a2 = 0.f, a3 = 0.f;
            #pragma unroll
            for (int j = 0; j < 9; ++j) {
                a0 = fmaf(wt.g[j], vv[0 + j], a0);
                a1 = fmaf(wt.g[j], vv[1 + j], a1);
                a2 = fmaf(wt.g[j], vv[2 + j], a2);
                a3 = fmaf(wt.g[j], vv[3 + j], a3);
            }
            wv.x = a0; wv.y = a1; wv.z = a2; wv.w = a3;
        }

        // push z-ring
        #pragma unroll
        for (int k = 0; k < 8; ++k) ring[k] = ring[k + 1];
        ring[8] = wv;

        // D-conv + clip + store
        if (i >= 8) {
            float a0 = 0.f, a1 = 0.f, a2 = 0.f, a3 = 0.f;
            #pragma unroll
            for (int j = 0; j < 9; ++j) {
                a0 = fmaf(wt.g[j], ring[j].x, a0);
                a1 = fmaf(wt.g[j], ring[j].y, a1);
                a2 = fmaf(wt.g[j], ring[j].z, a2);
                a3 = fmaf(wt.g[j], ring[j].w, a3);
            }
            float rr[4] = {a0, a1, a2, a3};
            float* po = out + (size_t)zo * 65536;
            #pragma unroll
            for (int e = 0; e < 4; ++e)
                po[ooff[e]] = fmaxf(fminf(cx[e], rr[e] + CLIPV), rr[e] - CLIPV);
        }

        // W-conv of next plane into sTt (same-wave DS order: after reads above)
        if (i < 39) wconv_write();
    }
}

extern "C" void kernel_launch(void* const* d_in, const int* in_sizes, int n_in,
                              void* d_out, int out_size, void* d_ws, size_t ws_size,
                              hipStream_t stream) {
    const float* x = (const float*)d_in[0];
    float* out = (float*)d_out;

    // normalized 1-D Gaussian weights (separable form of the reference kernel)
    W9 wt;
    {
        double g[9], s = 0.0;
        const double sigma = 9.0 / 4.0;
        for (int i = 0; i < 9; ++i) {
            double tt = (i - 4.0) / sigma;
            g[i] = exp(-0.5 * tt * tt);
            s += g[i];
        }
        for (int i = 0; i < 9; ++i) wt.g[i] = (float)(g[i] / s);
    }

    // 2048 single-wave blocks: 8 z-chunks (x32 planes) x 256 tiles (8x32)
    smooth3d_wave<<<dim3(2048), dim3(64), 0, stream>>>(x, out, wt);
}

// Round 5
// 61.615 us; speedup vs baseline: 1.6186x; 1.6186x over previous
//
#include <hip/hip_runtime.h>
#include <math.h>

#define CLIPV 0.03f

struct W9 { float g[9]; };

__device__ __forceinline__ int reflect_idx(int i, int n) {
    if (i < 0) i = -i;
    if (i >= n) i = 2 * n - 2 - i;
    return i;
}

// ---------------------------------------------------------------------------
// Pass 1: W-conv + H-conv. Zero LDS, zero barriers.
// One wave = one (z-plane, 32-row h-chunk). Lane owns 4 consecutive cols
// (wave = full 256-col row). Per h-step: 3 overlapping float4 loads (cols
// w-4..w+7, L1-hot), W-conv in registers, push into a 9-deep float4 H-ring
// (full unroll => static %9 indices, no ring movs), H-conv, float4 store.
// W-reflect handled branchlessly: edge lanes load a shifted f4 and reverse
// it via per-lane selects.
// Grid: 512 blocks x 256 thr = 2048 waves; bid&7 = XCD owns z in [32*xcd,..).
// ---------------------------------------------------------------------------
__global__ __launch_bounds__(256) void wh_pass(const float* __restrict__ x,
                                               float* __restrict__ tmp, W9 wt) {
    const int bid = blockIdx.x;
    const int z   = (bid & 7) * 32 + (bid >> 4);   // XCD-local z band
    const int sub = (bid >> 3) & 1;
    const int wv  = threadIdx.x >> 6;
    const int h0  = (sub * 4 + wv) * 32;           // this wave's output rows
    const int L   = threadIdx.x & 63;

    const float* plane  = x   + (size_t)z * 65536;
    float*       oplane = tmp + (size_t)z * 65536;

    const int  w4  = L * 4;
    const bool l0  = (L == 0), l63 = (L == 63);
    // lane 0: w-4..-1 reflect to 4,3,2,1 -> load {x1..x4} at off 1, reversed.
    // lane 63: w 256..259 reflect to 254..251 -> load {x251..x254}, reversed.
    const int offL = l0 ? 1 : (w4 - 4);
    const int offR = l63 ? 251 : (w4 + 4);

    float4 ring[9];

    #pragma unroll
    for (int i = 0; i < 40; ++i) {
        const int rin = reflect_idx(h0 - 4 + i, 256);
        const float* row = plane + rin * 256;
        const float4 Lf = *(const float4*)(row + offL);
        const float4 Cf = *(const float4*)(row + w4);
        const float4 Rf = *(const float4*)(row + offR);

        float sv[12];
        sv[0] = l0 ? Lf.w : Lf.x;
        sv[1] = l0 ? Lf.z : Lf.y;
        sv[2] = l0 ? Lf.y : Lf.z;
        sv[3] = l0 ? Lf.x : Lf.w;
        sv[4] = Cf.x; sv[5] = Cf.y; sv[6] = Cf.z; sv[7] = Cf.w;
        sv[8]  = l63 ? Rf.w : Rf.x;
        sv[9]  = l63 ? Rf.z : Rf.y;
        sv[10] = l63 ? Rf.y : Rf.z;
        sv[11] = l63 ? Rf.x : Rf.w;

        // W-conv -> one float4
        float4 wc;
        {
            float a0 = 0.f, a1 = 0.f, a2 = 0.f, a3 = 0.f;
            #pragma unroll
            for (int j = 0; j < 9; ++j) {
                a0 = fmaf(wt.g[j], sv[j],     a0);
                a1 = fmaf(wt.g[j], sv[j + 1], a1);
                a2 = fmaf(wt.g[j], sv[j + 2], a2);
                a3 = fmaf(wt.g[j], sv[j + 3], a3);
            }
            wc.x = a0; wc.y = a1; wc.z = a2; wc.w = a3;
        }
        ring[i % 9] = wc;   // static after full unroll

        // H-conv once ring holds rows hout-4..hout+4
        if (i >= 8) {
            float a0 = 0.f, a1 = 0.f, a2 = 0.f, a3 = 0.f;
            #pragma unroll
            for (int j = 0; j < 9; ++j) {
                const float4 v = ring[(i - 8 + j) % 9];
                a0 = fmaf(wt.g[j], v.x, a0);
                a1 = fmaf(wt.g[j], v.y, a1);
                a2 = fmaf(wt.g[j], v.z, a2);
                a3 = fmaf(wt.g[j], v.w, a3);
            }
            float4 o; o.x = a0; o.y = a1; o.z = a2; o.w = a3;
            *(float4*)(oplane + (h0 + i - 8) * 256 + w4) = o;
        }
    }
}

// ---------------------------------------------------------------------------
// Pass 2: D-conv + clip. Zero LDS, zero barriers. Thread owns one float4
// column, marches a z-chunk of 16 planes with a 9-deep float4 ring (full
// unroll). Grid: 1024 blocks; chunk -> XCD mapping matches pass 1 so tmp
// reads are L2-local.
// ---------------------------------------------------------------------------
__global__ __launch_bounds__(256) void d_clip_pass(const float* __restrict__ tmp,
                                                   const float* __restrict__ x,
                                                   float* __restrict__ out, W9 wt) {
    const int bid   = blockIdx.x;                         // 0..1023
    const int chunk = (bid & 7) * 2 + ((bid >> 3) & 1);   // 0..15 (XCD-local)
    const int tile  = bid >> 4;                           // 0..63
    const int z0    = chunk * 16;
    const size_t c4 = (size_t)tile * 256 + threadIdx.x;   // f4 index in plane

    const float4* t4 = (const float4*)tmp;
    const float4* xp = (const float4*)x;
    float4*       o4 = (float4*)out;

    float4 ring[9];
    #pragma unroll
    for (int k = 0; k < 8; ++k)
        ring[k] = t4[(size_t)reflect_idx(z0 - 4 + k, 256) * 16384 + c4];

    #pragma unroll
    for (int i = 0; i < 16; ++i) {
        const int z = z0 + i;
        ring[(8 + i) % 9] = t4[(size_t)reflect_idx(z + 4, 256) * 16384 + c4];
        const float4 xv = xp[(size_t)z * 16384 + c4];

        float a0 = 0.f, a1 = 0.f, a2 = 0.f, a3 = 0.f;
        #pragma unroll
        for (int j = 0; j < 9; ++j) {
            const float4 v = ring[(i + j) % 9];
            a0 = fmaf(wt.g[j], v.x, a0);
            a1 = fmaf(wt.g[j], v.y, a1);
            a2 = fmaf(wt.g[j], v.z, a2);
            a3 = fmaf(wt.g[j], v.w, a3);
        }
        float4 r;
        r.x = fmaxf(fminf(xv.x, a0 + CLIPV), a0 - CLIPV);
        r.y = fmaxf(fminf(xv.y, a1 + CLIPV), a1 - CLIPV);
        r.z = fmaxf(fminf(xv.z, a2 + CLIPV), a2 - CLIPV);
        r.w = fmaxf(fminf(xv.w, a3 + CLIPV), a3 - CLIPV);
        o4[(size_t)z * 16384 + c4] = r;
    }
}

extern "C" void kernel_launch(void* const* d_in, const int* in_sizes, int n_in,
                              void* d_out, int out_size, void* d_ws, size_t ws_size,
                              hipStream_t stream) {
    const float* x = (const float*)d_in[0];
    float* out = (float*)d_out;
    float* tmp = (float*)d_ws;   // 64 MB

    // normalized 1-D Gaussian weights (separable form of the reference kernel)
    W9 wt;
    {
        double g[9], s = 0.0;
        const double sigma = 9.0 / 4.0;
        for (int i = 0; i < 9; ++i) {
            double tt = (i - 4.0) / sigma;
            g[i] = exp(-0.5 * tt * tt);
            s += g[i];
        }
        for (int i = 0; i < 9; ++i) wt.g[i] = (float)(g[i] / s);
    }

    wh_pass<<<dim3(512), dim3(256), 0, stream>>>(x, tmp, wt);
    d_clip_pass<<<dim3(1024), dim3(256), 0, stream>>>(tmp, x, out, wt);
}